// Round 5
// baseline (1073.851 us; speedup 1.0000x reference)
//
#include <hip/hip_runtime.h>
#include <hip/hip_bf16.h>
#include <stdint.h>

#define B_   4
#define C_   256
#define C8_  32
#define HW_  4096
#define ROWS_ 320   // 32 Q + 32 K + 256 V composite rows
#define MS_  4      // m-split factor (across blocks; x2 more inside block)
#define L2E  1.4426950408889634f

typedef __attribute__((ext_vector_type(8)))  short  short8;
typedef __attribute__((ext_vector_type(8)))  ushort us8;
typedef __attribute__((ext_vector_type(2)))  float  f32x2;
typedef __attribute__((ext_vector_type(16))) float  f32x16;

// ---- workspace layout (bytes) ----
// All tensors FRAGMENT-MAJOR: 1KB frag = [64 lanes][8 ushort].
// Qf/Ktf: [b][blk32(128)][ks(2)]  lane=(q|m)&31 + 32*((e>>3)&1), j=e&7
// Vf:     [b][cblk(8)][mb(256)]   lane=c&31 + 32*((m>>3)&1),     j=m&7
// wbf:    [kc(16)][rowblk(10)]
#define WT_OFF    0
#define BALL_OFF  (256*320*4)
#define Q_OFF     (BALL_OFF + 1280)
#define KT_OFF    (Q_OFF  + B_*HW_*C8_*2)
#define V_OFF     (KT_OFF + B_*HW_*C8_*2)
#define PACC_OFF  (V_OFF  + B_*C_*HW_*2)
#define LPART_OFF (PACC_OFF + (size_t)MS_*B_*C_*HW_*2)
// total ~44.6 MB

__device__ __forceinline__ ushort f2bf(float f) {
    union { float f; uint32_t u; } v; v.f = f;
    uint32_t u = v.u;
    uint32_t r = u + 0x7fffu + ((u >> 16) & 1u);  // RNE
    return (ushort)(r >> 16);
}
__device__ __forceinline__ uint32_t pktr(float lo, float hi) {
    union { float f; uint32_t u; } a, b; a.f = lo; b.f = hi;
    return __builtin_amdgcn_perm(b.u, a.u, 0x07060302u);  // 1-instr trunc pack
}
// RNE pack of two f32 -> packed bf16 pair, single VALU op (no builtin; m240).
__device__ __forceinline__ uint32_t pkrne(float lo, float hi) {
    uint32_t r;
    asm("v_cvt_pk_bf16_f32 %0, %1, %2" : "=v"(r) : "v"(lo), "v"(hi));
    return r;
}
// Packed Schraudolph exp2 on a pair: v_pk_fma + v_pk_max + 2 cvt + 1 perm.
// Returns packed bf16 pair; e01 gets the two fp32 values for the l-sum.
__device__ __forceinline__ uint32_t fexp2_pk(float s0, float s1, f32x2& e01) {
    f32x2 s = {s0, s1};
    f32x2 y = __builtin_elementwise_fma(s, (f32x2)(8388608.0f),
                                        (f32x2)(1064992506.0f)); // (127-0.043)*2^23
    y = __builtin_elementwise_max(y, (f32x2)(0.0f));
    union { int i; float f; } c0, c1;
    c0.i = (int)y.x;  c1.i = (int)y.y;
    e01.x = c0.f;  e01.y = c1.f;
    return __builtin_amdgcn_perm((uint32_t)c1.i, (uint32_t)c0.i, 0x07060302u);
}

// ---------------- kernel 1: fold conv into weights (bf16, A-frag-major) ----
__global__ __launch_bounds__(256) void k_setup(
    const float* __restrict__ conv_w, const float* __restrict__ conv_b,
    const float* __restrict__ q_w, const float* __restrict__ q_b,
    const float* __restrict__ k_w, const float* __restrict__ k_b,
    const float* __restrict__ v_w, const float* __restrict__ v_b,
    ushort* __restrict__ wbf, float* __restrict__ ball)
{
    int r = blockIdx.x;        // 0..319 composite row
    int c = threadIdx.x;       // 0..255 input channel (k)
    const float* wrow;
    float bias;
    if (r < 32)       { wrow = q_w + r*32;      bias = q_b[r];      }
    else if (r < 64)  { wrow = k_w + (r-32)*32; bias = k_b[r-32];   }
    else              { wrow = v_w + (r-64)*32; bias = v_b[r-64];   }
    float acc = 0.f;
    #pragma unroll
    for (int d = 0; d < 32; ++d) acc += wrow[d] * conv_w[d*C_ + c];
    float scale = (r < 32) ? L2E : 1.0f;       // fold log2(e) into Q
    int lanew = (r & 31) + 32*((c >> 3) & 1);
    int fidx  = (c >> 4)*10 + (r >> 5);        // [kc][rowblk]
    wbf[fidx*512 + lanew*8 + (c & 7)] = f2bf(acc * scale);
    if (c == 0) {
        float bb = bias;
        #pragma unroll
        for (int d = 0; d < 32; ++d) bb += wrow[d] * conv_b[d];
        ball[r] = bb * scale;
    }
}

// ---------------- kernel 2: Q/Kt/V projection via MFMA + LDS transpose -----
// grid = B*128, 320 thr (5 waves = 320 rows x 32 n).
// R2: barrier-free wave-private transpose; unroll 4; cvt_pk epilogue.
__global__ __launch_bounds__(320) void k_qkv(
    const float* __restrict__ x, const ushort* __restrict__ wbf,
    const float* __restrict__ ball,
    ushort* __restrict__ qg, ushort* __restrict__ ktg, ushort* __restrict__ vg)
{
    __shared__ ushort tr[5][32*40];   // per-wave 32x32 transpose tile, stride 40

    int blk = blockIdx.x;
    int b  = blk >> 7;
    int nt = blk & 127;                // n-tile index (32 cols)
    int n0 = nt * 32;
    int t = threadIdx.x;
    int w = t >> 6, lane = t & 63;
    int l31 = lane & 31, h = lane >> 5;

    f32x16 acc[2];
    acc[0] = (f32x16)(0.f);
    acc[1] = (f32x16)(0.f);

    const float* xb = x + (size_t)b*C_*HW_ + n0 + l31;

    #pragma unroll 4
    for (int kc = 0; kc < 16; ++kc) {          // K chunks of 16
        short8 a0 = *(const short8*)(wbf + (kc*10 + w*2    )*512 + lane*8);
        short8 a1 = *(const short8*)(wbf + (kc*10 + w*2 + 1)*512 + lane*8);
        const float* xc = xb + (size_t)(kc*16 + h*8)*HW_;
        float xv[8];
        #pragma unroll
        for (int j = 0; j < 8; ++j) xv[j] = xc[(size_t)j*HW_];
        union { uint32_t d[4]; short8 s8; } bf;
        #pragma unroll
        for (int j2 = 0; j2 < 4; ++j2) bf.d[j2] = pktr(xv[2*j2], xv[2*j2+1]);
        acc[0] = __builtin_amdgcn_mfma_f32_32x32x16_bf16(a0, bf.s8, acc[0], 0, 0, 0);
        acc[1] = __builtin_amdgcn_mfma_f32_32x32x16_bf16(a1, bf.s8, acc[1], 0, 0, 0);
    }

    // epilogue: per mi subtile, transpose in LDS (wave-private, barrier-free),
    // store contiguous frags
    #pragma unroll
    for (int mi = 0; mi < 2; ++mi) {
        int rowb = w*64 + mi*32;
        bool isQK = (rowb < 64);
        float4 bv[4];
        #pragma unroll
        for (int g = 0; g < 4; ++g)
            bv[g] = *(const float4*)(ball + rowb + g*8 + 4*h);
        if (isQK) {
            #pragma unroll
            for (int p = 0; p < 8; ++p) {
                int r0 = 2*p;
                int g  = r0 >> 2;
                int i0 = r0 & 3;           // 0 or 2
                float f0 = acc[mi][r0]     + ((const float*)&bv[g])[i0];
                float f1 = acc[mi][r0 + 1] + ((const float*)&bv[g])[i0 + 1];
                uint32_t pk = pkrne(f0, f1);
                int roff0 = i0 + 8*g + 4*h;          // consecutive pair
                *(uint32_t*)(&tr[w][l31*40 + roff0]) = pk;
            }
            #pragma unroll
            for (int f = 0; f < 2; ++f) {
                us8 frag = *(const us8*)(&tr[w][l31*40 + f*16 + h*8]);
                ushort* dstb = (rowb == 0) ? qg : ktg;
                size_t ad = ((size_t)((b*128 + nt)*2 + f) << 9) + lane*8;
                *(us8*)(dstb + ad) = frag;
            }
        } else {
            #pragma unroll
            for (int p = 0; p < 8; ++p) {
                int r0 = 2*p;
                int g  = r0 >> 2;
                int i0 = r0 & 3;
                float f0 = acc[mi][r0]     + ((const float*)&bv[g])[i0];
                float f1 = acc[mi][r0 + 1] + ((const float*)&bv[g])[i0 + 1];
                uint32_t pk = pkrne(f0, f1);
                int roff0 = i0 + 8*g + 4*h;
                tr[w][(roff0    )*40 + l31] = (ushort)pk;
                tr[w][(roff0 + 1)*40 + l31] = (ushort)(pk >> 16);
            }
            #pragma unroll
            for (int f = 0; f < 2; ++f) {
                us8 frag = *(const us8*)(&tr[w][l31*40 + f*16 + h*8]);
                int cblk = (rowb - 64) >> 5;
                int mb = nt*2 + f;
                size_t ad = ((size_t)((b*8 + cblk)*256 + mb) << 9) + lane*8;
                *(us8*)(vg + ad) = frag;
            }
        }
    }
}

// ---------------- kernel 3: flash attention, m-split partials ----------------
// grid = 512 blocks x 1024 thr (16 waves): ms=blk&3, cs=bit2, qb=bits[3:6],
// b=bits[7:8]. R4: in-block key-split -- wave-group mg=w>>3 handles keys
// it*128 + mg*64; 8 iters. 80KB LDS (2buf x 2grp), 2 blocks/CU -> 32 waves/CU
// = 8 waves/SIMD (was 4): doubles latency hiding, which R1/R3 showed
// instruction-order fixes could not provide. Same total MFMA/VALU/LDS work;
// one-time cross-group acc+lsum reduce via LDS epilogue (f32x2 pair layout,
// 2-way bank aliasing = free per m136). pacc/lpart layout unchanged (MS_=4).
// R0: permlane32_swap S->PV exchange (T12); setprio around MFMA (T5).
// R1: within-wave 2-stage pipeline (kept).
// R3: counted-vmcnt triple-buffer was null (STAGE issued pre-compute means
//     the syncthreads drain was already ~free) -- reverted to dbuf+barrier.
__global__ __launch_bounds__(1024, 8) void k_attn(
    const ushort* __restrict__ qg, const ushort* __restrict__ ktg,
    const ushort* __restrict__ vg,
    ushort* __restrict__ pacc, float* __restrict__ lpart)
{
    __shared__ ushort v_lds[2][2][16*512];   // [buf][grp] 16 V frags = 64KB
    __shared__ ushort kt_lds[2][2][4*512];   // [buf][grp] 4 Kt frags = 16KB

    int blk = blockIdx.x;
    int ms = blk & 3;
    int cs = (blk >> 2) & 1;
    int qb = (blk >> 3) & 15;
    int b  = blk >> 7;
    int t = threadIdx.x;
    int wv = t >> 6, lane = t & 63;
    int mg = wv >> 3, wl = wv & 7;
    int l31 = lane & 31, h = lane >> 5;
    int mbase = ms*1024 + mg*64;   // group's first key tile; stride 128/iter

    // Q fragments: contiguous 1KB loads; wave (mg,wl) owns qblk = qb*8 + wl
    short8 qf[2];
    #pragma unroll
    for (int ks = 0; ks < 2; ++ks)
        qf[ks] = *(const short8*)(qg
            + ((size_t)((b*128 + qb*8 + wl)*2 + ks) << 9) + lane*8);

    f32x16 acc[4];
    #pragma unroll
    for (int j = 0; j < 4; ++j) acc[j] = (f32x16)(0.f);
    f32x2 lacc0 = {0.f, 0.f};
    f32x2 lacc1 = {0.f, 0.f};

    // staging (per group): V 16 frags -> 2/wave ; Kt 4 frags -> waves wl<4
    #define STAGE(bi, m0)                                                           \
    {                                                                               \
        _Pragma("unroll")                                                           \
        for (int ff = 0; ff < 2; ++ff) {                                            \
            int f = wl*2 + ff;                                                      \
            int cfr = f >> 2, mf = f & 3;                                           \
            const ushort* src = vg + ((size_t)((b*8 + cs*4 + cfr)*256               \
                                 + ((m0) >> 4) + mf) << 9) + lane*8;                \
            __builtin_amdgcn_global_load_lds(                                       \
                (const __attribute__((address_space(1))) uint32_t*)src,             \
                (__attribute__((address_space(3))) uint32_t*)&v_lds[bi][mg][f*512], \
                16, 0, 0);                                                          \
        }                                                                           \
        if (wl < 4) {                                                               \
            const ushort* src = ktg + ((size_t)((b*128 + ((m0) >> 5) + (wl >> 1))*2 \
                                 + (wl & 1)) << 9) + lane*8;                        \
            __builtin_amdgcn_global_load_lds(                                       \
                (const __attribute__((address_space(1))) uint32_t*)src,             \
                (__attribute__((address_space(3))) uint32_t*)&kt_lds[bi][mg][wl*512],\
                16, 0, 0);                                                          \
        }                                                                           \
    }

    // permlane merge: result0 = {a.lo, b.lo}, result1 = {a.hi, b.hi}
    #define PMERGE(uu, lo8, hi8)                                                    \
    {                                                                               \
        union { uint32_t d[4]; short8 s8; } fe_, fo_;                               \
        auto r02 = __builtin_amdgcn_permlane32_swap((int)uu[0], (int)uu[2], false, false); \
        auto r13 = __builtin_amdgcn_permlane32_swap((int)uu[1], (int)uu[3], false, false); \
        auto r46 = __builtin_amdgcn_permlane32_swap((int)uu[4], (int)uu[6], false, false); \
        auto r57 = __builtin_amdgcn_permlane32_swap((int)uu[5], (int)uu[7], false, false); \
        fe_.d[0] = (uint32_t)r02[0];  fe_.d[1] = (uint32_t)r13[0];                  \
        fe_.d[2] = (uint32_t)r02[1];  fe_.d[3] = (uint32_t)r13[1];                  \
        fo_.d[0] = (uint32_t)r46[0];  fo_.d[1] = (uint32_t)r57[0];                  \
        fo_.d[2] = (uint32_t)r46[1];  fo_.d[3] = (uint32_t)r57[1];                  \
        lo8 = fe_.s8;  hi8 = fo_.s8;                                               \
    }

    STAGE(0, mbase)
    __syncthreads();

    int buf = 0;
    #pragma unroll 1
    for (int it = 0; it < 8; ++it) {
        if (it + 1 < 8) STAGE(buf ^ 1, mbase + (it+1)*128)

        const ushort* vbuf = &v_lds[buf][mg][0];
        const ushort* kbuf = &kt_lds[buf][mg][0];

        // ---- QK kb=0 (head cluster, prio-boosted) ----
        short8 kt0a = *(const short8*)(kbuf + 0*512 + lane*8);
        short8 kt1a = *(const short8*)(kbuf + 1*512 + lane*8);
        f32x16 s_a = (f32x16)(0.f);
        __builtin_amdgcn_s_setprio(1);
        s_a = __builtin_amdgcn_mfma_f32_32x32x16_bf16(kt0a, qf[0], s_a, 0, 0, 0);
        s_a = __builtin_amdgcn_mfma_f32_32x32x16_bf16(kt1a, qf[1], s_a, 0, 0, 0);
        __builtin_amdgcn_s_setprio(0);

        // ---- SM_a: exp2 + pack + permlane ----
        uint32_t ua[8];
        #pragma unroll
        for (int i = 0; i < 8; ++i) {
            f32x2 e01;
            ua[i] = fexp2_pk(s_a[2*i], s_a[2*i+1], e01);
            if (i & 1) lacc1 += e01; else lacc0 += e01;
        }
        short8 pfa0, pfa1;
        PMERGE(ua, pfa0, pfa1)

        // ---- QK kb=1 (issued early; executes under SM_a tail / PV_a head) ----
        short8 kt0b = *(const short8*)(kbuf + 2*512 + lane*8);
        short8 kt1b = *(const short8*)(kbuf + 3*512 + lane*8);
        f32x16 s_b = (f32x16)(0.f);
        s_b = __builtin_amdgcn_mfma_f32_32x32x16_bf16(kt0b, qf[0], s_b, 0, 0, 0);
        s_b = __builtin_amdgcn_mfma_f32_32x32x16_bf16(kt1b, qf[1], s_b, 0, 0, 0);

        // ---- fence-free region: SM_b VALU interleaves with PV_a MFMA ----
        uint32_t ub[8];
        #pragma unroll
        for (int i = 0; i < 8; ++i) {
            f32x2 e01;
            ub[i] = fexp2_pk(s_b[2*i], s_b[2*i+1], e01);
            if (i & 1) lacc1 += e01; else lacc0 += e01;
        }
        #pragma unroll
        for (int msub = 0; msub < 2; ++msub) {     // PV_a: keys [0,32)
            short8 pfm = msub ? pfa1 : pfa0;
            int ks16 = msub;
            #pragma unroll
            for (int cfr = 0; cfr < 4; ++cfr) {
                short8 vf = *(const short8*)(vbuf + (cfr*4 + ks16)*512 + lane*8);
                acc[cfr] = __builtin_amdgcn_mfma_f32_32x32x16_bf16(vf, pfm, acc[cfr], 0, 0, 0);
            }
        }
        short8 pfb0, pfb1;
        PMERGE(ub, pfb0, pfb1)

        // ---- PV_b (tail cluster, prio-boosted) ----
        __builtin_amdgcn_s_setprio(1);
        #pragma unroll
        for (int msub = 0; msub < 2; ++msub) {     // keys [32,64)
            short8 pfm = msub ? pfb1 : pfb0;
            int ks16 = 2 + msub;
            #pragma unroll
            for (int cfr = 0; cfr < 4; ++cfr) {
                short8 vf = *(const short8*)(vbuf + (cfr*4 + ks16)*512 + lane*8);
                acc[cfr] = __builtin_amdgcn_mfma_f32_32x32x16_bf16(vf, pfm, acc[cfr], 0, 0, 0);
            }
        }
        __builtin_amdgcn_s_setprio(0);

        __syncthreads();
        buf ^= 1;
    }

    // per-wave l finalize: horizontal + other lane-half's key contributions
    f32x2 lacc = lacc0 + lacc1;
    float lsum = lacc.x + lacc.y;
    {
        union { float f; int i; } cv; cv.f = lsum;
        cv.i = __shfl_xor(cv.i, 32);
        lsum += cv.f;
    }

    // ---- cross-group reduce (group 1 -> group 0) via reused LDS ----
    // layout: red[p*1024 + wl*128 + lane*2] f32x2 pairs (stride 2 dwords
    // per lane = 2-way bank aliasing = free). 16 pairs/chunk = acc[0..1].
    float* red  = (float*)&v_lds[0][0][0];    // 64 KB scratch
    float* lred = (float*)&kt_lds[0][0][0];   // 16 KB scratch

    if (mg == 1) {
        if (h == 0) lred[wl*32 + l31] = lsum;
        #pragma unroll
        for (int p = 0; p < 16; ++p) {
            int a = p >> 3, i = (p & 7) * 2;
            f32x2 v2 = { acc[a][i], acc[a][i+1] };
            *(f32x2*)(red + p*1024 + wl*128 + lane*2) = v2;
        }
    }
    __syncthreads();
    if (mg == 0) {
        lsum += lred[wl*32 + l31];
        #pragma unroll
        for (int p = 0; p < 16; ++p) {
            int a = p >> 3, i = (p & 7) * 2;
            f32x2 v2 = *(const f32x2*)(red + p*1024 + wl*128 + lane*2);
            acc[a][i] += v2.x;  acc[a][i+1] += v2.y;
        }
    }
    __syncthreads();
    if (mg == 1) {
        #pragma unroll
        for (int p = 0; p < 16; ++p) {
            int a = 2 + (p >> 3), i = (p & 7) * 2;
            f32x2 v2 = { acc[a][i], acc[a][i+1] };
            *(f32x2*)(red + p*1024 + wl*128 + lane*2) = v2;
        }
    }
    __syncthreads();
    if (mg == 0) {
        #pragma unroll
        for (int p = 0; p < 16; ++p) {
            int a = 2 + (p >> 3), i = (p & 7) * 2;
            f32x2 v2 = *(const f32x2*)(red + p*1024 + wl*128 + lane*2);
            acc[a][i] += v2.x;  acc[a][i+1] += v2.y;
        }

        if (cs == 0 && h == 0)
            lpart[(size_t)(ms*B_ + b)*HW_ + qb*256 + wl*32 + l31] = lsum;

        // pacc raw fragment dump: contiguous 2KB per cfr wave-store
        int blkl = ((ms*B_ + b)*16 + qb)*2 + cs;
        #pragma unroll
        for (int cfr = 0; cfr < 4; ++cfr) {
            union { uint32_t d[8]; us8 hlf[2]; } pk;
            #pragma unroll
            for (int i = 0; i < 8; ++i)
                pk.d[i] = pktr(acc[cfr][2*i], acc[cfr][2*i+1]);
            ushort* dst = pacc + ((size_t)(blkl*32 + wl*4 + cfr) << 10);
            *(us8*)(dst + lane*8)       = pk.hlf[0];
            *(us8*)(dst + 512 + lane*8) = pk.hlf[1];
        }
    }
    #undef STAGE
    #undef PMERGE
}

// ---------------- kernel 4: combine via LDS transpose + epilogue ----------
// grid = 1024 blocks (b,qb,cs,w), 256 thr. Phase 1: frag-native decode +
// gamma/l fold -> LDS [128c][36]. Phase 2: float4 x/out (full lines).
__global__ __launch_bounds__(256) void k_comb(
    const ushort* __restrict__ pacc, const float* __restrict__ lpart,
    const float* __restrict__ x, const float* __restrict__ gamma_p,
    float* __restrict__ out)
{
    __shared__ float lds_acc[128*36];   // 18.4 KB

    int blk = blockIdx.x;
    int w  = blk & 7;
    int cs = (blk >> 3) & 1;
    int qb = (blk >> 4) & 15;
    int b  = blk >> 8;
    int t = threadIdx.x;

    int l31 = t & 31;
    int h   = (t >> 5) & 1;
    int cfr = (t >> 6) & 3;
    int q = qb*256 + w*32 + l31;
    int lanef = h*32 + l31;

    float sum[16];
    #pragma unroll
    for (int k = 0; k < 16; ++k) sum[k] = 0.f;
    float lt = 0.f;

    #pragma unroll
    for (int ms = 0; ms < MS_; ++ms) {
        int blkl = ((ms*B_ + b)*16 + qb)*2 + cs;
        const ushort* pp = pacc + ((size_t)(blkl*32 + w*4 + cfr) << 10) + lanef*8;
        us8 a0 = *(const us8*)pp;
        us8 a1 = *(const us8*)(pp + 512);
        #pragma unroll
        for (int k = 0; k < 8; ++k) {
            union { uint32_t u; float f; } cv;
            cv.u = ((uint32_t)a0[k]) << 16;  sum[k]   += cv.f;
            cv.u = ((uint32_t)a1[k]) << 16;  sum[k+8] += cv.f;
        }
        lt += lpart[(size_t)(ms*B_ + b)*HW_ + q];
    }

    float rl = gamma_p[0] / lt;
    #pragma unroll
    for (int k = 0; k < 16; ++k) {
        int c = cfr*32 + (k & 3) + 8*(k >> 2) + 4*h;
        lds_acc[c*36 + l31] = sum[k]*rl;
    }
    __syncthreads();

    // phase 2: 1024 float4 slots [c(128)][qg(8)]; thread does 4 slots
    const float* xb = x + ((size_t)(b*C_ + cs*128))*HW_ + qb*256 + w*32;
    float* ob = out + ((size_t)(b*C_ + cs*128))*HW_ + qb*256 + w*32;
    #pragma unroll
    for (int i = 0; i < 4; ++i) {
        int s = t + i*256;
        int c = s >> 3, qg = s & 7;
        float4 a = *(const float4*)(&lds_acc[c*36 + qg*4]);
        size_t off = (size_t)c*HW_ + qg*4;
        float4 xv = *(const float4*)(xb + off);
        a.x += xv.x; a.y += xv.y; a.z += xv.z; a.w += xv.w;
        *(float4*)(ob + off) = a;
    }
}

extern "C" void kernel_launch(void* const* d_in, const int* in_sizes, int n_in,
                              void* d_out, int out_size, void* d_ws, size_t ws_size,
                              hipStream_t stream)
{
    const float* x      = (const float*)d_in[0];
    const float* conv_w = (const float*)d_in[1];
    const float* conv_b = (const float*)d_in[2];
    const float* q_w    = (const float*)d_in[3];
    const float* q_b    = (const float*)d_in[4];
    const float* k_w    = (const float*)d_in[5];
    const float* k_b    = (const float*)d_in[6];
    const float* v_w    = (const float*)d_in[7];
    const float* v_b    = (const float*)d_in[8];
    const float* gamma  = (const float*)d_in[9];
    float* out = (float*)d_out;

    char* ws = (char*)d_ws;
    ushort* wbf   = (ushort*)(ws + WT_OFF);
    float*  ball  = (float*)(ws + BALL_OFF);
    ushort* qg    = (ushort*)(ws + Q_OFF);
    ushort* ktg   = (ushort*)(ws + KT_OFF);
    ushort* vg    = (ushort*)(ws + V_OFF);
    ushort* pacc  = (ushort*)(ws + PACC_OFF);
    float*  lpart = (float*)(ws + LPART_OFF);

    k_setup<<<ROWS_, 256, 0, stream>>>(conv_w, conv_b, q_w, q_b, k_w, k_b,
                                       v_w, v_b, wbf, ball);
    k_qkv<<<B_*128, 320, 0, stream>>>(x, wbf, ball, qg, ktg, vg);
    k_attn<<<512, 1024, 0, stream>>>(qg, ktg, vg, pacc, lpart);
    k_comb<<<1024, 256, 0, stream>>>(pacc, lpart, x, gamma, out);
}

// Round 7
// 344.816 us; speedup vs baseline: 3.1143x; 3.1143x over previous
//
#include <hip/hip_runtime.h>
#include <hip/hip_bf16.h>
#include <stdint.h>

#define B_   4
#define C_   256
#define C8_  32
#define HW_  4096
#define ROWS_ 320   // 32 Q + 32 K + 256 V composite rows
#define MS_  4      // m-split factor
#define NB_  512    // grid size (co-resident: 2 blocks/CU x 256 CU)
#define L2E  1.4426950408889634f

typedef __attribute__((ext_vector_type(8)))  short  short8;
typedef __attribute__((ext_vector_type(8)))  ushort us8;
typedef __attribute__((ext_vector_type(2)))  float  f32x2;
typedef __attribute__((ext_vector_type(16))) float  f32x16;

// ---- workspace layout (bytes) ----
#define WT_OFF    0
#define BALL_OFF  (256*320*4)
#define Q_OFF     (BALL_OFF + 1280)
#define KT_OFF    (Q_OFF  + B_*HW_*C8_*2)
#define V_OFF     (KT_OFF + B_*HW_*C8_*2)
#define PACC_OFF  (V_OFF  + B_*C_*HW_*2)
#define LPART_OFF (PACC_OFF + (size_t)MS_*B_*C_*HW_*2)
#define GB_OFF    (LPART_OFF + (size_t)MS_*B_*HW_*4)   // grid-barrier cnt/gen

__device__ __forceinline__ ushort f2bf(float f) {
    union { float f; uint32_t u; } v; v.f = f;
    uint32_t u = v.u;
    uint32_t r = u + 0x7fffu + ((u >> 16) & 1u);  // RNE
    return (ushort)(r >> 16);
}
__device__ __forceinline__ uint32_t pktr(float lo, float hi) {
    union { float f; uint32_t u; } a, b; a.f = lo; b.f = hi;
    return __builtin_amdgcn_perm(b.u, a.u, 0x07060302u);  // 1-instr trunc pack
}
// RNE pack of two f32 -> packed bf16 pair, single VALU op.
__device__ __forceinline__ uint32_t pkrne(float lo, float hi) {
    uint32_t r;
    asm("v_cvt_pk_bf16_f32 %0, %1, %2" : "=v"(r) : "v"(lo), "v"(hi));
    return r;
}
// Packed Schraudolph exp2 on a pair.
__device__ __forceinline__ uint32_t fexp2_pk(float s0, float s1, f32x2& e01) {
    f32x2 s = {s0, s1};
    f32x2 y = __builtin_elementwise_fma(s, (f32x2)(8388608.0f),
                                        (f32x2)(1064992506.0f)); // (127-0.043)*2^23
    y = __builtin_elementwise_max(y, (f32x2)(0.0f));
    union { int i; float f; } c0, c1;
    c0.i = (int)y.x;  c1.i = (int)y.y;
    e01.x = c0.f;  e01.y = c1.f;
    return __builtin_amdgcn_perm((uint32_t)c1.i, (uint32_t)c0.i, 0x07060302u);
}

// Replay-safe grid barrier (R6): cnt/gen zeroed by captured hipMemsetAsync
// before each launch. Release: __threadfence (XCD L2 writeback) + acq_rel
// fetch_add. Last arriver resets cnt (ordered before the RELEASE gen bump).
// Spinners: relaxed agent loads (coherent point) + trailing acquire fence.
// Bounded spin: converts a residency failure into wrong-answer, not a hang.
__device__ __forceinline__ void gridbar(uint32_t* cnt, uint32_t* gen) {
    __syncthreads();
    if (threadIdx.x == 0) {
        __threadfence();   // release: this XCD's dirty L2 -> coherent point
        uint32_t g = __hip_atomic_load(gen, __ATOMIC_RELAXED,
                                       __HIP_MEMORY_SCOPE_AGENT);
        uint32_t old = __hip_atomic_fetch_add(cnt, 1u, __ATOMIC_ACQ_REL,
                                              __HIP_MEMORY_SCOPE_AGENT);
        if (old == NB_ - 1u) {
            __hip_atomic_store(cnt, 0u, __ATOMIC_RELAXED,
                               __HIP_MEMORY_SCOPE_AGENT);
            __hip_atomic_fetch_add(gen, 1u, __ATOMIC_RELEASE,
                                   __HIP_MEMORY_SCOPE_AGENT);
        } else {
            long tmo = 200000000;
            while (__hip_atomic_load(gen, __ATOMIC_RELAXED,
                                     __HIP_MEMORY_SCOPE_AGENT) == g
                   && --tmo > 0) ;
        }
        __threadfence();   // acquire: invalidate L1/L2 before next phase reads
    }
    __syncthreads();
}

// ================= fused pipeline: setup -> qkv -> attn -> comb =============
// R5/R6: single kernel, 512 blocks x 512 thr (= k_attn's proven geometry),
// hand-rolled grid barrier between phases (cooperative launch failed under
// graph capture -- R5 output was never written). 40KB smem union.
// __launch_bounds__(512,4) caps VGPR at 128 AND guarantees 2 blocks/CU
// co-residency for the barrier (R4 lesson: (1024,8) forced 64-cap -> spill).
// Phase 2 is the R1-measured attn body (best k_attn: 54.5us), unmodified.
__global__ __launch_bounds__(512, 4) void k_fused(
    const float* __restrict__ x,
    const float* __restrict__ conv_w, const float* __restrict__ conv_b,
    const float* __restrict__ q_w, const float* __restrict__ q_b,
    const float* __restrict__ k_w, const float* __restrict__ k_b,
    const float* __restrict__ v_w, const float* __restrict__ v_b,
    const float* __restrict__ gamma_p,
    float* __restrict__ out,
    ushort* __restrict__ wbf, float* __restrict__ ball,
    ushort* __restrict__ qg, ushort* __restrict__ ktg, ushort* __restrict__ vg,
    ushort* __restrict__ pacc, float* __restrict__ lpart,
    uint32_t* __restrict__ gb)
{
    __shared__ __align__(16) char smem[40960];

    int blk = blockIdx.x;
    int t = threadIdx.x;
    uint32_t* gb_cnt = gb;
    uint32_t* gb_gen = gb + 1;

    // ---------------- phase 0: fold conv into weights --------------------
    if (blk < ROWS_ && t < 256) {
        int r = blk;               // composite row
        int c = t;                 // input channel
        const float* wrow;
        float bias;
        if (r < 32)       { wrow = q_w + r*32;      bias = q_b[r];      }
        else if (r < 64)  { wrow = k_w + (r-32)*32; bias = k_b[r-32];   }
        else              { wrow = v_w + (r-64)*32; bias = v_b[r-64];   }
        float acc = 0.f;
        #pragma unroll
        for (int d = 0; d < 32; ++d) acc += wrow[d] * conv_w[d*C_ + c];
        float scale = (r < 32) ? L2E : 1.0f;       // fold log2(e) into Q
        int lanew = (r & 31) + 32*((c >> 3) & 1);
        int fidx  = (c >> 4)*10 + (r >> 5);        // [kc][rowblk]
        wbf[fidx*512 + lanew*8 + (c & 7)] = f2bf(acc * scale);
        if (c == 0) {
            float bb = bias;
            #pragma unroll
            for (int d = 0; d < 32; ++d) bb += wrow[d] * conv_b[d];
            ball[r] = bb * scale;
        }
    }
    gridbar(gb_cnt, gb_gen);

    // ---------------- phase 1: Q/Kt/V projection -------------------------
    if (t < 320) {
        ushort (*tr)[32*40] = (ushort (*)[32*40])smem;   // per-wave 32x32 tile

        int b  = blk >> 7;
        int nt = blk & 127;
        int n0 = nt * 32;
        int w = t >> 6, lane = t & 63;
        int l31 = lane & 31, h = lane >> 5;

        f32x16 acc[2];
        acc[0] = (f32x16)(0.f);
        acc[1] = (f32x16)(0.f);

        const float* xb = x + (size_t)b*C_*HW_ + n0 + l31;

        #pragma unroll 4
        for (int kc = 0; kc < 16; ++kc) {
            short8 a0 = *(const short8*)(wbf + (kc*10 + w*2    )*512 + lane*8);
            short8 a1 = *(const short8*)(wbf + (kc*10 + w*2 + 1)*512 + lane*8);
            const float* xc = xb + (size_t)(kc*16 + h*8)*HW_;
            float xv[8];
            #pragma unroll
            for (int j = 0; j < 8; ++j) xv[j] = xc[(size_t)j*HW_];
            union { uint32_t d[4]; short8 s8; } bf;
            #pragma unroll
            for (int j2 = 0; j2 < 4; ++j2) bf.d[j2] = pktr(xv[2*j2], xv[2*j2+1]);
            acc[0] = __builtin_amdgcn_mfma_f32_32x32x16_bf16(a0, bf.s8, acc[0], 0, 0, 0);
            acc[1] = __builtin_amdgcn_mfma_f32_32x32x16_bf16(a1, bf.s8, acc[1], 0, 0, 0);
        }

        #pragma unroll
        for (int mi = 0; mi < 2; ++mi) {
            int rowb = w*64 + mi*32;
            bool isQK = (rowb < 64);
            float4 bv[4];
            #pragma unroll
            for (int g = 0; g < 4; ++g)
                bv[g] = *(const float4*)(ball + rowb + g*8 + 4*h);
            if (isQK) {
                #pragma unroll
                for (int p = 0; p < 8; ++p) {
                    int r0 = 2*p;
                    int g  = r0 >> 2;
                    int i0 = r0 & 3;
                    float f0 = acc[mi][r0]     + ((const float*)&bv[g])[i0];
                    float f1 = acc[mi][r0 + 1] + ((const float*)&bv[g])[i0 + 1];
                    uint32_t pk = pkrne(f0, f1);
                    int roff0 = i0 + 8*g + 4*h;
                    *(uint32_t*)(&tr[w][l31*40 + roff0]) = pk;
                }
                #pragma unroll
                for (int f = 0; f < 2; ++f) {
                    us8 frag = *(const us8*)(&tr[w][l31*40 + f*16 + h*8]);
                    ushort* dstb = (rowb == 0) ? qg : ktg;
                    size_t ad = ((size_t)((b*128 + nt)*2 + f) << 9) + lane*8;
                    *(us8*)(dstb + ad) = frag;
                }
            } else {
                #pragma unroll
                for (int p = 0; p < 8; ++p) {
                    int r0 = 2*p;
                    int g  = r0 >> 2;
                    int i0 = r0 & 3;
                    float f0 = acc[mi][r0]     + ((const float*)&bv[g])[i0];
                    float f1 = acc[mi][r0 + 1] + ((const float*)&bv[g])[i0 + 1];
                    uint32_t pk = pkrne(f0, f1);
                    int roff0 = i0 + 8*g + 4*h;
                    tr[w][(roff0    )*40 + l31] = (ushort)pk;
                    tr[w][(roff0 + 1)*40 + l31] = (ushort)(pk >> 16);
                }
                #pragma unroll
                for (int f = 0; f < 2; ++f) {
                    us8 frag = *(const us8*)(&tr[w][l31*40 + f*16 + h*8]);
                    int cblk = (rowb - 64) >> 5;
                    int mb = nt*2 + f;
                    size_t ad = ((size_t)((b*8 + cblk)*256 + mb) << 9) + lane*8;
                    *(us8*)(vg + ad) = frag;
                }
            }
        }
    }
    gridbar(gb_cnt, gb_gen);

    // ---------------- phase 2: flash attention (R1 structure) -------------
    {
        ushort* v_lds  = (ushort*)smem;              // [2][16*512] = 32KB
        ushort* kt_lds = (ushort*)(smem + 32768);    // [2][4*512]  = 8KB

        int ms = blk & 3;
        int cs = (blk >> 2) & 1;
        int qb = (blk >> 3) & 15;
        int b  = blk >> 7;
        int w = t >> 6, lane = t & 63;
        int l31 = lane & 31, h = lane >> 5;
        int mbase = ms*1024;

        short8 qf[2];
        #pragma unroll
        for (int ks = 0; ks < 2; ++ks)
            qf[ks] = *(const short8*)(qg
                + ((size_t)((b*128 + qb*8 + w)*2 + ks) << 9) + lane*8);

        f32x16 acc[4];
        #pragma unroll
        for (int j = 0; j < 4; ++j) acc[j] = (f32x16)(0.f);
        f32x2 lacc0 = {0.f, 0.f};
        f32x2 lacc1 = {0.f, 0.f};

        #define STAGE(bi, m0)                                                          \
        {                                                                              \
            _Pragma("unroll")                                                          \
            for (int ff = 0; ff < 2; ++ff) {                                           \
                int f = w*2 + ff;                                                      \
                int cfr = f >> 2, mf = f & 3;                                          \
                const ushort* src = vg + ((size_t)((b*8 + cs*4 + cfr)*256              \
                                     + ((m0) >> 4) + mf) << 9) + lane*8;               \
                __builtin_amdgcn_global_load_lds(                                      \
                    (const __attribute__((address_space(1))) uint32_t*)src,            \
                    (__attribute__((address_space(3))) uint32_t*)                      \
                        &v_lds[(bi)*8192 + f*512],                                     \
                    16, 0, 0);                                                         \
            }                                                                          \
            if (w < 4) {                                                               \
                const ushort* src = ktg + ((size_t)((b*128 + ((m0) >> 5) + (w >> 1))*2 \
                                     + (w & 1)) << 9) + lane*8;                        \
                __builtin_amdgcn_global_load_lds(                                      \
                    (const __attribute__((address_space(1))) uint32_t*)src,            \
                    (__attribute__((address_space(3))) uint32_t*)                      \
                        &kt_lds[(bi)*2048 + w*512],                                    \
                    16, 0, 0);                                                         \
            }                                                                          \
        }

        #define PMERGE(uu, lo8, hi8)                                                   \
        {                                                                              \
            union { uint32_t d[4]; short8 s8; } fe_, fo_;                              \
            auto r02 = __builtin_amdgcn_permlane32_swap((int)uu[0], (int)uu[2], false, false); \
            auto r13 = __builtin_amdgcn_permlane32_swap((int)uu[1], (int)uu[3], false, false); \
            auto r46 = __builtin_amdgcn_permlane32_swap((int)uu[4], (int)uu[6], false, false); \
            auto r57 = __builtin_amdgcn_permlane32_swap((int)uu[5], (int)uu[7], false, false); \
            fe_.d[0] = (uint32_t)r02[0];  fe_.d[1] = (uint32_t)r13[0];                 \
            fe_.d[2] = (uint32_t)r02[1];  fe_.d[3] = (uint32_t)r13[1];                 \
            fo_.d[0] = (uint32_t)r46[0];  fo_.d[1] = (uint32_t)r57[0];                 \
            fo_.d[2] = (uint32_t)r46[1];  fo_.d[3] = (uint32_t)r57[1];                 \
            lo8 = fe_.s8;  hi8 = fo_.s8;                                              \
        }

        STAGE(0, mbase)
        __syncthreads();

        int buf = 0;
        for (int it = 0; it < 16; ++it) {
            if (it + 1 < 16) STAGE(buf ^ 1, mbase + (it+1)*64)

            const ushort* vbuf = &v_lds[buf*8192];
            const ushort* kbuf = &kt_lds[buf*2048];

            // ---- QK kb=0 (head cluster, prio-boosted) ----
            short8 kt0a = *(const short8*)(kbuf + 0*512 + lane*8);
            short8 kt1a = *(const short8*)(kbuf + 1*512 + lane*8);
            f32x16 s_a = (f32x16)(0.f);
            __builtin_amdgcn_s_setprio(1);
            s_a = __builtin_amdgcn_mfma_f32_32x32x16_bf16(kt0a, qf[0], s_a, 0, 0, 0);
            s_a = __builtin_amdgcn_mfma_f32_32x32x16_bf16(kt1a, qf[1], s_a, 0, 0, 0);
            __builtin_amdgcn_s_setprio(0);

            // ---- SM_a ----
            uint32_t ua[8];
            #pragma unroll
            for (int i = 0; i < 8; ++i) {
                f32x2 e01;
                ua[i] = fexp2_pk(s_a[2*i], s_a[2*i+1], e01);
                if (i & 1) lacc1 += e01; else lacc0 += e01;
            }
            short8 pfa0, pfa1;
            PMERGE(ua, pfa0, pfa1)

            // ---- QK kb=1 ----
            short8 kt0b = *(const short8*)(kbuf + 2*512 + lane*8);
            short8 kt1b = *(const short8*)(kbuf + 3*512 + lane*8);
            f32x16 s_b = (f32x16)(0.f);
            s_b = __builtin_amdgcn_mfma_f32_32x32x16_bf16(kt0b, qf[0], s_b, 0, 0, 0);
            s_b = __builtin_amdgcn_mfma_f32_32x32x16_bf16(kt1b, qf[1], s_b, 0, 0, 0);

            // ---- SM_b || PV_a (fence-free) ----
            uint32_t ub[8];
            #pragma unroll
            for (int i = 0; i < 8; ++i) {
                f32x2 e01;
                ub[i] = fexp2_pk(s_b[2*i], s_b[2*i+1], e01);
                if (i & 1) lacc1 += e01; else lacc0 += e01;
            }
            #pragma unroll
            for (int msub = 0; msub < 2; ++msub) {     // PV_a: keys [0,32)
                short8 pfm = msub ? pfa1 : pfa0;
                int ks16 = msub;
                #pragma unroll
                for (int cfr = 0; cfr < 4; ++cfr) {
                    short8 vf = *(const short8*)(vbuf + (cfr*4 + ks16)*512 + lane*8);
                    acc[cfr] = __builtin_amdgcn_mfma_f32_32x32x16_bf16(vf, pfm, acc[cfr], 0, 0, 0);
                }
            }
            short8 pfb0, pfb1;
            PMERGE(ub, pfb0, pfb1)

            // ---- PV_b (tail cluster, prio-boosted) ----
            __builtin_amdgcn_s_setprio(1);
            #pragma unroll
            for (int msub = 0; msub < 2; ++msub) {     // keys [32,64)
                short8 pfm = msub ? pfb1 : pfb0;
                int ks16 = 2 + msub;
                #pragma unroll
                for (int cfr = 0; cfr < 4; ++cfr) {
                    short8 vf = *(const short8*)(vbuf + (cfr*4 + ks16)*512 + lane*8);
                    acc[cfr] = __builtin_amdgcn_mfma_f32_32x32x16_bf16(vf, pfm, acc[cfr], 0, 0, 0);
                }
            }
            __builtin_amdgcn_s_setprio(0);

            __syncthreads();
            buf ^= 1;
        }

        // finalize l
        f32x2 lacc = lacc0 + lacc1;
        float lsum = lacc.x + lacc.y;
        {
            union { float f; int i; } cv; cv.f = lsum;
            cv.i = __shfl_xor(cv.i, 32);
            lsum += cv.f;
        }
        if (cs == 0 && h == 0)
            lpart[(size_t)(ms*B_ + b)*HW_ + qb*256 + w*32 + l31] = lsum;

        // pacc raw fragment dump
        int blkl = ((ms*B_ + b)*16 + qb)*2 + cs;
        #pragma unroll
        for (int cfr = 0; cfr < 4; ++cfr) {
            union { uint32_t d[8]; us8 hlf[2]; } pk;
            #pragma unroll
            for (int i = 0; i < 8; ++i)
                pk.d[i] = pktr(acc[cfr][2*i], acc[cfr][2*i+1]);
            ushort* dst = pacc + ((size_t)(blkl*32 + w*4 + cfr) << 10);
            *(us8*)(dst + lane*8)       = pk.hlf[0];
            *(us8*)(dst + 512 + lane*8) = pk.hlf[1];
        }
        #undef STAGE
        #undef PMERGE
    }
    gridbar(gb_cnt, gb_gen);

    // ---------------- phase 3: combine + epilogue -------------------------
    // two virtual 256-thread comb blocks per real block: vb = blk*2 + (t>>8)
    {
        int half = t >> 8;
        int tl = t & 255;
        int vb = blk*2 + half;

        int w3  = vb & 7;
        int cs3 = (vb >> 3) & 1;
        int qb3 = (vb >> 4) & 15;
        int b3  = vb >> 8;

        float* lds_acc = (float*)(smem + half*18432);   // 128*36 floats each

        int l31 = tl & 31;
        int h3  = (tl >> 5) & 1;
        int cfr = (tl >> 6) & 3;
        int q = qb3*256 + w3*32 + l31;
        int lanef = h3*32 + l31;

        float sum[16];
        #pragma unroll
        for (int k = 0; k < 16; ++k) sum[k] = 0.f;
        float lt = 0.f;

        #pragma unroll
        for (int ms = 0; ms < MS_; ++ms) {
            int blkl = ((ms*B_ + b3)*16 + qb3)*2 + cs3;
            const ushort* pp = pacc + ((size_t)(blkl*32 + w3*4 + cfr) << 10) + lanef*8;
            us8 a0 = *(const us8*)pp;
            us8 a1 = *(const us8*)(pp + 512);
            #pragma unroll
            for (int k = 0; k < 8; ++k) {
                union { uint32_t u; float f; } cv;
                cv.u = ((uint32_t)a0[k]) << 16;  sum[k]   += cv.f;
                cv.u = ((uint32_t)a1[k]) << 16;  sum[k+8] += cv.f;
            }
            lt += lpart[(size_t)(ms*B_ + b3)*HW_ + q];
        }

        float rl = gamma_p[0] / lt;
        #pragma unroll
        for (int k = 0; k < 16; ++k) {
            int c = cfr*32 + (k & 3) + 8*(k >> 2) + 4*h3;
            lds_acc[c*36 + l31] = sum[k]*rl;
        }
        __syncthreads();

        const float* xb = x + ((size_t)(b3*C_ + cs3*128))*HW_ + qb3*256 + w3*32;
        float* ob = out + ((size_t)(b3*C_ + cs3*128))*HW_ + qb3*256 + w3*32;
        #pragma unroll
        for (int i = 0; i < 4; ++i) {
            int s = tl + i*256;
            int c = s >> 3, qg2 = s & 7;
            float4 a = *(const float4*)(&lds_acc[c*36 + qg2*4]);
            size_t off = (size_t)c*HW_ + qg2*4;
            float4 xv = *(const float4*)(xb + off);
            a.x += xv.x; a.y += xv.y; a.z += xv.z; a.w += xv.w;
            *(float4*)(ob + off) = a;
        }
    }
}

extern "C" void kernel_launch(void* const* d_in, const int* in_sizes, int n_in,
                              void* d_out, int out_size, void* d_ws, size_t ws_size,
                              hipStream_t stream)
{
    const float* x      = (const float*)d_in[0];
    const float* conv_w = (const float*)d_in[1];
    const float* conv_b = (const float*)d_in[2];
    const float* q_w    = (const float*)d_in[3];
    const float* q_b    = (const float*)d_in[4];
    const float* k_w    = (const float*)d_in[5];
    const float* k_b    = (const float*)d_in[6];
    const float* v_w    = (const float*)d_in[7];
    const float* v_b    = (const float*)d_in[8];
    const float* gamma  = (const float*)d_in[9];
    float* out = (float*)d_out;

    char* ws = (char*)d_ws;
    ushort* wbf   = (ushort*)(ws + WT_OFF);
    float*  ball  = (float*)(ws + BALL_OFF);
    ushort* qg    = (ushort*)(ws + Q_OFF);
    ushort* ktg   = (ushort*)(ws + KT_OFF);
    ushort* vg    = (ushort*)(ws + V_OFF);
    ushort* pacc  = (ushort*)(ws + PACC_OFF);
    float*  lpart = (float*)(ws + LPART_OFF);
    uint32_t* gb  = (uint32_t*)(ws + GB_OFF);

    // zero the barrier state each launch (captured into the graph)
    hipMemsetAsync(gb, 0, 64, stream);

    k_fused<<<NB_, 512, 0, stream>>>(
        x, conv_w, conv_b, q_w, q_b, k_w, k_b, v_w, v_b, gamma, out,
        wbf, ball, qg, ktg, vg, pacc, lpart, gb);
}

// Round 8
// 190.635 us; speedup vs baseline: 5.6330x; 1.8088x over previous
//
#include <hip/hip_runtime.h>
#include <hip/hip_bf16.h>
#include <stdint.h>

#define B_   4
#define C_   256
#define C8_  32
#define HW_  4096
#define ROWS_ 320   // 32 Q + 32 K + 256 V composite rows
#define MS_  4      // m-split factor
#define L2E  1.4426950408889634f

typedef __attribute__((ext_vector_type(8)))  short  short8;
typedef __attribute__((ext_vector_type(8)))  ushort us8;
typedef __attribute__((ext_vector_type(2)))  float  f32x2;
typedef __attribute__((ext_vector_type(16))) float  f32x16;

// ---- workspace layout (bytes) ----
#define WT_OFF    0
#define BALL_OFF  (256*320*4)
#define Q_OFF     (BALL_OFF + 1280)
#define KT_OFF    (Q_OFF  + B_*HW_*C8_*2)
#define V_OFF     (KT_OFF + B_*HW_*C8_*2)
#define PACC_OFF  (V_OFF  + B_*C_*HW_*2)
#define LPART_OFF (PACC_OFF + (size_t)MS_*B_*C_*HW_*2)
#define CNT_OFF   (LPART_OFF + (size_t)MS_*B_*HW_*4)   // fan-in counters (128 u32)

__device__ __forceinline__ ushort f2bf(float f) {
    union { float f; uint32_t u; } v; v.f = f;
    uint32_t u = v.u;
    uint32_t r = u + 0x7fffu + ((u >> 16) & 1u);  // RNE
    return (ushort)(r >> 16);
}
__device__ __forceinline__ uint32_t pktr(float lo, float hi) {
    union { float f; uint32_t u; } a, b; a.f = lo; b.f = hi;
    return __builtin_amdgcn_perm(b.u, a.u, 0x07060302u);  // 1-instr trunc pack
}
// Packed Schraudolph exp2 on a pair: v_pk_fma + v_pk_max + 2 cvt + 1 perm.
__device__ __forceinline__ uint32_t fexp2_pk(float s0, float s1, f32x2& e01) {
    f32x2 s = {s0, s1};
    f32x2 y = __builtin_elementwise_fma(s, (f32x2)(8388608.0f),
                                        (f32x2)(1064992506.0f)); // (127-0.043)*2^23
    y = __builtin_elementwise_max(y, (f32x2)(0.0f));
    union { int i; float f; } c0, c1;
    c0.i = (int)y.x;  c1.i = (int)y.y;
    e01.x = c0.f;  e01.y = c1.f;
    return __builtin_amdgcn_perm((uint32_t)c1.i, (uint32_t)c0.i, 0x07060302u);
}

// ---------------- kernel 1: fold conv into weights (bf16, A-frag-major) ----
__global__ __launch_bounds__(256) void k_setup(
    const float* __restrict__ conv_w, const float* __restrict__ conv_b,
    const float* __restrict__ q_w, const float* __restrict__ q_b,
    const float* __restrict__ k_w, const float* __restrict__ k_b,
    const float* __restrict__ v_w, const float* __restrict__ v_b,
    ushort* __restrict__ wbf, float* __restrict__ ball)
{
    int r = blockIdx.x;        // 0..319 composite row
    int c = threadIdx.x;       // 0..255 input channel (k)
    const float* wrow;
    float bias;
    if (r < 32)       { wrow = q_w + r*32;      bias = q_b[r];      }
    else if (r < 64)  { wrow = k_w + (r-32)*32; bias = k_b[r-32];   }
    else              { wrow = v_w + (r-64)*32; bias = v_b[r-64];   }
    float acc = 0.f;
    #pragma unroll
    for (int d = 0; d < 32; ++d) acc += wrow[d] * conv_w[d*C_ + c];
    float scale = (r < 32) ? L2E : 1.0f;       // fold log2(e) into Q
    int lanew = (r & 31) + 32*((c >> 3) & 1);
    int fidx  = (c >> 4)*10 + (r >> 5);        // [kc][rowblk]
    wbf[fidx*512 + lanew*8 + (c & 7)] = f2bf(acc * scale);
    if (c == 0) {
        float bb = bias;
        #pragma unroll
        for (int d = 0; d < 32; ++d) bb += wrow[d] * conv_b[d];
        ball[r] = bb * scale;
    }
}

// ---------------- kernel 2: Q/Kt/V projection via MFMA + LDS transpose -----
// grid = B*128, 320 thr (5 waves = 320 rows x 32 n). R1-measured version.
__global__ __launch_bounds__(320) void k_qkv(
    const float* __restrict__ x, const ushort* __restrict__ wbf,
    const float* __restrict__ ball,
    ushort* __restrict__ qg, ushort* __restrict__ ktg, ushort* __restrict__ vg)
{
    __shared__ ushort tr[5][32*40];   // per-wave 32x32 transpose tile, stride 40

    int blk = blockIdx.x;
    int b  = blk >> 7;
    int nt = blk & 127;                // n-tile index (32 cols)
    int n0 = nt * 32;
    int t = threadIdx.x;
    int w = t >> 6, lane = t & 63;
    int l31 = lane & 31, h = lane >> 5;

    f32x16 acc[2];
    acc[0] = (f32x16)(0.f);
    acc[1] = (f32x16)(0.f);

    const float* xb = x + (size_t)b*C_*HW_ + n0 + l31;

    #pragma unroll 2
    for (int kc = 0; kc < 16; ++kc) {          // K chunks of 16
        short8 a0 = *(const short8*)(wbf + (kc*10 + w*2    )*512 + lane*8);
        short8 a1 = *(const short8*)(wbf + (kc*10 + w*2 + 1)*512 + lane*8);
        const float* xc = xb + (size_t)(kc*16 + h*8)*HW_;
        union { uint32_t d[4]; short8 s8; } bf;
        #pragma unroll
        for (int j2 = 0; j2 < 4; ++j2) {
            float f0 = xc[(size_t)(2*j2    )*HW_];
            float f1 = xc[(size_t)(2*j2 + 1)*HW_];
            bf.d[j2] = pktr(f0, f1);
        }
        acc[0] = __builtin_amdgcn_mfma_f32_32x32x16_bf16(a0, bf.s8, acc[0], 0, 0, 0);
        acc[1] = __builtin_amdgcn_mfma_f32_32x32x16_bf16(a1, bf.s8, acc[1], 0, 0, 0);
    }

    // epilogue: per mi subtile, transpose in LDS, store contiguous frags
    #pragma unroll
    for (int mi = 0; mi < 2; ++mi) {
        int rowb = w*64 + mi*32;
        bool isQK = (rowb < 64);
        #pragma unroll
        for (int r = 0; r < 16; ++r) {
            int roff = (r & 3) + 8*(r >> 2) + 4*h;
            ushort bv = f2bf(acc[mi][r] + ball[rowb + roff]);
            int ad = isQK ? (l31*40 + roff) : (roff*40 + l31);
            tr[w][ad] = bv;
        }
        __syncthreads();
        #pragma unroll
        for (int f = 0; f < 2; ++f) {
            us8 frag = *(const us8*)(&tr[w][l31*40 + f*16 + h*8]);
            if (isQK) {
                ushort* dstb = (rowb == 0) ? qg : ktg;
                size_t ad = ((size_t)((b*128 + nt)*2 + f) << 9) + lane*8;
                *(us8*)(dstb + ad) = frag;
            } else {
                int cblk = (rowb - 64) >> 5;
                int mb = nt*2 + f;
                size_t ad = ((size_t)((b*8 + cblk)*256 + mb) << 9) + lane*8;
                *(us8*)(vg + ad) = frag;
            }
        }
        __syncthreads();
    }
}

// ---------------- kernel 3: flash attention + fan-in combine ----------------
// grid = 512 x 512 thr. Main loop = R1-measured best (152.9us config).
// R7: k_comb absorbed via atomic fan-in (split-K pattern): after pacc/lpart
// stores, thread0 release-fences + fetch_adds cnt[b][qb][cs]; the 4th arriver
// acquire-fences and combines its (b,qb,cs) tile (8 w-subtiles, 4 iters x
// 2 halves, LDS reused as 2x18.4KB). Both cs write lpart (bitwise-identical
// values -- benign race) so each cs counter is self-sufficient. No global
// barrier (R6 lesson: barrier+fence fusion cost ~170us idle). Fail-closed:
// fan-in bug => missing tile => absmax failure.
__global__ __launch_bounds__(512, 4) void k_attn(
    const ushort* __restrict__ qg, const ushort* __restrict__ ktg,
    const ushort* __restrict__ vg,
    ushort* __restrict__ pacc, float* __restrict__ lpart,
    const float* __restrict__ x, const float* __restrict__ gamma_p,
    float* __restrict__ out, uint32_t* __restrict__ cnt)
{
    __shared__ __align__(16) char smem[40960];
    __shared__ int comb_flag;
    ushort* v_lds  = (ushort*)smem;              // [2][16*512] = 32KB
    ushort* kt_lds = (ushort*)(smem + 32768);    // [2][4*512]  = 8KB

    int blk = blockIdx.x;
    int ms = blk & 3;
    int cs = (blk >> 2) & 1;
    int qb = (blk >> 3) & 15;
    int b  = blk >> 7;
    int t = threadIdx.x;
    int w = t >> 6, lane = t & 63;
    int l31 = lane & 31, h = lane >> 5;
    int mbase = ms*1024;

    short8 qf[2];
    #pragma unroll
    for (int ks = 0; ks < 2; ++ks)
        qf[ks] = *(const short8*)(qg
            + ((size_t)((b*128 + qb*8 + w)*2 + ks) << 9) + lane*8);

    f32x16 acc[4];
    #pragma unroll
    for (int j = 0; j < 4; ++j) acc[j] = (f32x16)(0.f);
    f32x2 lacc0 = {0.f, 0.f};
    f32x2 lacc1 = {0.f, 0.f};

    #define STAGE(bi, m0)                                                          \
    {                                                                              \
        _Pragma("unroll")                                                          \
        for (int ff = 0; ff < 2; ++ff) {                                           \
            int f = w*2 + ff;                                                      \
            int cfr = f >> 2, mf = f & 3;                                          \
            const ushort* src = vg + ((size_t)((b*8 + cs*4 + cfr)*256              \
                                 + ((m0) >> 4) + mf) << 9) + lane*8;               \
            __builtin_amdgcn_global_load_lds(                                      \
                (const __attribute__((address_space(1))) uint32_t*)src,            \
                (__attribute__((address_space(3))) uint32_t*)                      \
                    &v_lds[(bi)*8192 + f*512],                                     \
                16, 0, 0);                                                         \
        }                                                                          \
        if (w < 4) {                                                               \
            const ushort* src = ktg + ((size_t)((b*128 + ((m0) >> 5) + (w >> 1))*2 \
                                 + (w & 1)) << 9) + lane*8;                        \
            __builtin_amdgcn_global_load_lds(                                      \
                (const __attribute__((address_space(1))) uint32_t*)src,            \
                (__attribute__((address_space(3))) uint32_t*)                      \
                    &kt_lds[(bi)*2048 + w*512],                                    \
                16, 0, 0);                                                         \
        }                                                                          \
    }

    #define PMERGE(uu, lo8, hi8)                                                   \
    {                                                                              \
        union { uint32_t d[4]; short8 s8; } fe_, fo_;                              \
        auto r02 = __builtin_amdgcn_permlane32_swap((int)uu[0], (int)uu[2], false, false); \
        auto r13 = __builtin_amdgcn_permlane32_swap((int)uu[1], (int)uu[3], false, false); \
        auto r46 = __builtin_amdgcn_permlane32_swap((int)uu[4], (int)uu[6], false, false); \
        auto r57 = __builtin_amdgcn_permlane32_swap((int)uu[5], (int)uu[7], false, false); \
        fe_.d[0] = (uint32_t)r02[0];  fe_.d[1] = (uint32_t)r13[0];                 \
        fe_.d[2] = (uint32_t)r02[1];  fe_.d[3] = (uint32_t)r13[1];                 \
        fo_.d[0] = (uint32_t)r46[0];  fo_.d[1] = (uint32_t)r57[0];                 \
        fo_.d[2] = (uint32_t)r46[1];  fo_.d[3] = (uint32_t)r57[1];                 \
        lo8 = fe_.s8;  hi8 = fo_.s8;                                              \
    }

    STAGE(0, mbase)
    __syncthreads();

    int buf = 0;
    for (int it = 0; it < 16; ++it) {
        if (it + 1 < 16) STAGE(buf ^ 1, mbase + (it+1)*64)

        const ushort* vbuf = &v_lds[buf*8192];
        const ushort* kbuf = &kt_lds[buf*2048];

        // ---- QK kb=0 (head cluster, prio-boosted) ----
        short8 kt0a = *(const short8*)(kbuf + 0*512 + lane*8);
        short8 kt1a = *(const short8*)(kbuf + 1*512 + lane*8);
        f32x16 s_a = (f32x16)(0.f);
        __builtin_amdgcn_s_setprio(1);
        s_a = __builtin_amdgcn_mfma_f32_32x32x16_bf16(kt0a, qf[0], s_a, 0, 0, 0);
        s_a = __builtin_amdgcn_mfma_f32_32x32x16_bf16(kt1a, qf[1], s_a, 0, 0, 0);
        __builtin_amdgcn_s_setprio(0);

        // ---- SM_a ----
        uint32_t ua[8];
        #pragma unroll
        for (int i = 0; i < 8; ++i) {
            f32x2 e01;
            ua[i] = fexp2_pk(s_a[2*i], s_a[2*i+1], e01);
            if (i & 1) lacc1 += e01; else lacc0 += e01;
        }
        short8 pfa0, pfa1;
        PMERGE(ua, pfa0, pfa1)

        // ---- QK kb=1 (issued early) ----
        short8 kt0b = *(const short8*)(kbuf + 2*512 + lane*8);
        short8 kt1b = *(const short8*)(kbuf + 3*512 + lane*8);
        f32x16 s_b = (f32x16)(0.f);
        s_b = __builtin_amdgcn_mfma_f32_32x32x16_bf16(kt0b, qf[0], s_b, 0, 0, 0);
        s_b = __builtin_amdgcn_mfma_f32_32x32x16_bf16(kt1b, qf[1], s_b, 0, 0, 0);

        // ---- SM_b || PV_a (fence-free) ----
        uint32_t ub[8];
        #pragma unroll
        for (int i = 0; i < 8; ++i) {
            f32x2 e01;
            ub[i] = fexp2_pk(s_b[2*i], s_b[2*i+1], e01);
            if (i & 1) lacc1 += e01; else lacc0 += e01;
        }
        #pragma unroll
        for (int msub = 0; msub < 2; ++msub) {     // PV_a: keys [0,32)
            short8 pfm = msub ? pfa1 : pfa0;
            int ks16 = msub;
            #pragma unroll
            for (int cfr = 0; cfr < 4; ++cfr) {
                short8 vf = *(const short8*)(vbuf + (cfr*4 + ks16)*512 + lane*8);
                acc[cfr] = __builtin_amdgcn_mfma_f32_32x32x16_bf16(vf, pfm, acc[cfr], 0, 0, 0);
            }
        }
        short8 pfb0, pfb1;
        PMERGE(ub, pfb0, pfb1)

        // ---- PV_b (tail cluster, prio-boosted) ----
        __builtin_amdgcn_s_setprio(1);
        #pragma unroll
        for (int msub = 0; msub < 2; ++msub) {     // keys [32,64)
            short8 pfm = msub ? pfb1 : pfb0;
            int ks16 = 2 + msub;
            #pragma unroll
            for (int cfr = 0; cfr < 4; ++cfr) {
                short8 vf = *(const short8*)(vbuf + (cfr*4 + ks16)*512 + lane*8);
                acc[cfr] = __builtin_amdgcn_mfma_f32_32x32x16_bf16(vf, pfm, acc[cfr], 0, 0, 0);
            }
        }
        __builtin_amdgcn_s_setprio(0);

        __syncthreads();
        buf ^= 1;
    }

    // finalize l (identical for cs=0/1 -> both write; benign identical race)
    f32x2 lacc = lacc0 + lacc1;
    float lsum = lacc.x + lacc.y;
    {
        union { float f; int i; } cv; cv.f = lsum;
        cv.i = __shfl_xor(cv.i, 32);
        lsum += cv.f;
    }
    if (h == 0)
        lpart[(size_t)(ms*B_ + b)*HW_ + qb*256 + w*32 + l31] = lsum;

    // pacc raw fragment dump: contiguous 2KB per cfr wave-store
    int blkl = ((ms*B_ + b)*16 + qb)*2 + cs;
    #pragma unroll
    for (int cfr = 0; cfr < 4; ++cfr) {
        union { uint32_t d[8]; us8 hlf[2]; } pk;
        #pragma unroll
        for (int i = 0; i < 8; ++i)
            pk.d[i] = pktr(acc[cfr][2*i], acc[cfr][2*i+1]);
        ushort* dst = pacc + ((size_t)(blkl*32 + w*4 + cfr) << 10);
        *(us8*)(dst + lane*8)       = pk.hlf[0];
        *(us8*)(dst + 512 + lane*8) = pk.hlf[1];
    }

    // ---- fan-in: 4th arriver for (b,qb,cs) combines the tile ----
    __syncthreads();                  // drains all stores (vmcnt 0 at barrier)
    if (t == 0) {
        __threadfence();              // release: pacc/lpart -> coherent point
        uint32_t old = __hip_atomic_fetch_add(&cnt[(b*16 + qb)*2 + cs], 1u,
                           __ATOMIC_ACQ_REL, __HIP_MEMORY_SCOPE_AGENT);
        comb_flag = (old == MS_ - 1u) ? 1 : 0;
        if (comb_flag) __threadfence();   // acquire: invalidate L1/L2 view
    }
    __syncthreads();

    if (comb_flag) {
        int half = t >> 8;            // two virtual 256-thr comb blocks
        int tl = t & 255;
        int l31c = tl & 31;
        int h3   = (tl >> 5) & 1;
        int cfr3 = (tl >> 6) & 3;
        int lanef = h3*32 + l31c;
        float* lds_acc = (float*)(smem + half*18432);   // 128*36 floats each
        float gmv = gamma_p[0];

        #pragma unroll 1
        for (int wq = 0; wq < 4; ++wq) {
            int w3 = wq*2 + half;
            int q = qb*256 + w3*32 + l31c;

            float sum[16];
            #pragma unroll
            for (int k = 0; k < 16; ++k) sum[k] = 0.f;
            float lt = 0.f;

            #pragma unroll
            for (int msx = 0; msx < MS_; ++msx) {
                int bl2 = ((msx*B_ + b)*16 + qb)*2 + cs;
                const ushort* pp = pacc
                    + ((size_t)(bl2*32 + w3*4 + cfr3) << 10) + lanef*8;
                us8 a0 = *(const us8*)pp;
                us8 a1 = *(const us8*)(pp + 512);
                #pragma unroll
                for (int k = 0; k < 8; ++k) {
                    union { uint32_t u; float f; } cv;
                    cv.u = ((uint32_t)a0[k]) << 16;  sum[k]   += cv.f;
                    cv.u = ((uint32_t)a1[k]) << 16;  sum[k+8] += cv.f;
                }
                lt += lpart[(size_t)(msx*B_ + b)*HW_ + q];
            }

            float rl = gmv / lt;
            #pragma unroll
            for (int k = 0; k < 16; ++k) {
                int c = cfr3*32 + (k & 3) + 8*(k >> 2) + 4*h3;
                lds_acc[c*36 + l31c] = sum[k]*rl;
            }
            __syncthreads();

            const float* xb2 = x + ((size_t)(b*C_ + cs*128))*HW_ + qb*256 + w3*32;
            float* ob = out + ((size_t)(b*C_ + cs*128))*HW_ + qb*256 + w3*32;
            #pragma unroll
            for (int i = 0; i < 4; ++i) {
                int s = tl + i*256;
                int c = s >> 3, qg2 = s & 7;
                float4 a = *(const float4*)(&lds_acc[c*36 + qg2*4]);
                size_t off = (size_t)c*HW_ + qg2*4;
                float4 xv = *(const float4*)(xb2 + off);
                a.x += xv.x; a.y += xv.y; a.z += xv.z; a.w += xv.w;
                *(float4*)(ob + off) = a;
            }
            __syncthreads();
        }
    }
    #undef STAGE
    #undef PMERGE
}

extern "C" void kernel_launch(void* const* d_in, const int* in_sizes, int n_in,
                              void* d_out, int out_size, void* d_ws, size_t ws_size,
                              hipStream_t stream)
{
    const float* x      = (const float*)d_in[0];
    const float* conv_w = (const float*)d_in[1];
    const float* conv_b = (const float*)d_in[2];
    const float* q_w    = (const float*)d_in[3];
    const float* q_b    = (const float*)d_in[4];
    const float* k_w    = (const float*)d_in[5];
    const float* k_b    = (const float*)d_in[6];
    const float* v_w    = (const float*)d_in[7];
    const float* v_b    = (const float*)d_in[8];
    const float* gamma  = (const float*)d_in[9];
    float* out = (float*)d_out;

    char* ws = (char*)d_ws;
    ushort* wbf   = (ushort*)(ws + WT_OFF);
    float*  ball  = (float*)(ws + BALL_OFF);
    ushort* qg    = (ushort*)(ws + Q_OFF);
    ushort* ktg   = (ushort*)(ws + KT_OFF);
    ushort* vg    = (ushort*)(ws + V_OFF);
    ushort* pacc  = (ushort*)(ws + PACC_OFF);
    float*  lpart = (float*)(ws + LPART_OFF);
    uint32_t* cnt = (uint32_t*)(ws + CNT_OFF);

    hipMemsetAsync(cnt, 0, 512, stream);   // zero fan-in counters (capture-safe)

    k_setup<<<ROWS_, 256, 0, stream>>>(conv_w, conv_b, q_w, q_b, k_w, k_b,
                                       v_w, v_b, wbf, ball);
    k_qkv<<<B_*128, 320, 0, stream>>>(x, wbf, ball, qg, ktg, vg);
    k_attn<<<512, 512, 0, stream>>>(qg, ktg, vg, pacc, lpart,
                                    x, gamma, out, cnt);
}

// Round 9
// 150.164 us; speedup vs baseline: 7.1512x; 1.2695x over previous
//
#include <hip/hip_runtime.h>
#include <hip/hip_bf16.h>
#include <stdint.h>

#define B_   4
#define C_   256
#define C8_  32
#define HW_  4096
#define ROWS_ 320   // 32 Q + 32 K + 256 V composite rows
#define MS_  4      // m-split factor
#define L2E  1.4426950408889634f

typedef __attribute__((ext_vector_type(8)))  short  short8;
typedef __attribute__((ext_vector_type(8)))  ushort us8;
typedef __attribute__((ext_vector_type(2)))  float  f32x2;
typedef __attribute__((ext_vector_type(16))) float  f32x16;

// ---- workspace layout (bytes) ----
#define WT_OFF    0
#define BALL_OFF  (256*320*4)
#define Q_OFF     (BALL_OFF + 1280)
#define KT_OFF    (Q_OFF  + B_*HW_*C8_*2)
#define V_OFF     (KT_OFF + B_*HW_*C8_*2)
#define PACC_OFF  (V_OFF  + B_*C_*HW_*2)
#define LPART_OFF (PACC_OFF + (size_t)MS_*B_*C_*HW_*2)

__device__ __forceinline__ ushort f2bf(float f) {
    union { float f; uint32_t u; } v; v.f = f;
    uint32_t u = v.u;
    uint32_t r = u + 0x7fffu + ((u >> 16) & 1u);  // RNE
    return (ushort)(r >> 16);
}
__device__ __forceinline__ uint32_t pktr(float lo, float hi) {
    union { float f; uint32_t u; } a, b; a.f = lo; b.f = hi;
    return __builtin_amdgcn_perm(b.u, a.u, 0x07060302u);  // 1-instr trunc pack
}
// Packed Schraudolph exp2 on a pair: v_pk_fma + v_pk_max + 2 cvt + 1 perm.
__device__ __forceinline__ uint32_t fexp2_pk(float s0, float s1, f32x2& e01) {
    f32x2 s = {s0, s1};
    f32x2 y = __builtin_elementwise_fma(s, (f32x2)(8388608.0f),
                                        (f32x2)(1064992506.0f)); // (127-0.043)*2^23
    y = __builtin_elementwise_max(y, (f32x2)(0.0f));
    union { int i; float f; } c0, c1;
    c0.i = (int)y.x;  c1.i = (int)y.y;
    e01.x = c0.f;  e01.y = c1.f;
    return __builtin_amdgcn_perm((uint32_t)c1.i, (uint32_t)c0.i, 0x07060302u);
}

// ---------------- kernel 1: fold conv into weights (bf16, A-frag-major) ----
__global__ __launch_bounds__(256) void k_setup(
    const float* __restrict__ conv_w, const float* __restrict__ conv_b,
    const float* __restrict__ q_w, const float* __restrict__ q_b,
    const float* __restrict__ k_w, const float* __restrict__ k_b,
    const float* __restrict__ v_w, const float* __restrict__ v_b,
    ushort* __restrict__ wbf, float* __restrict__ ball)
{
    int r = blockIdx.x;        // 0..319 composite row
    int c = threadIdx.x;       // 0..255 input channel (k)
    const float* wrow;
    float bias;
    if (r < 32)       { wrow = q_w + r*32;      bias = q_b[r];      }
    else if (r < 64)  { wrow = k_w + (r-32)*32; bias = k_b[r-32];   }
    else              { wrow = v_w + (r-64)*32; bias = v_b[r-64];   }
    float acc = 0.f;
    #pragma unroll
    for (int d = 0; d < 32; ++d) acc += wrow[d] * conv_w[d*C_ + c];
    float scale = (r < 32) ? L2E : 1.0f;       // fold log2(e) into Q
    int lanew = (r & 31) + 32*((c >> 3) & 1);
    int fidx  = (c >> 4)*10 + (r >> 5);        // [kc][rowblk]
    wbf[fidx*512 + lanew*8 + (c & 7)] = f2bf(acc * scale);
    if (c == 0) {
        float bb = bias;
        #pragma unroll
        for (int d = 0; d < 32; ++d) bb += wrow[d] * conv_b[d];
        ball[r] = bb * scale;
    }
}

// ---------------- kernel 2: Q/Kt/V projection via MFMA + LDS transpose -----
// grid = B*128, 320 thr (5 waves = 320 rows x 32 n).
// R8: bulk-stage the block's x tile (256c x 32n = 32KB) to LDS ONCE via
// global_load_lds (waves 0..3, 8 x 1KB chunks each, all in flight). The R1
// version had every wave issue the SAME 128 strided 4B global loads
// (B-operand is w-independent) -- 5x redundant, latency-bound. B-fragments
// now come from 8 ds_read_b32/lane (bank=l31 for all rows -> 2 lanes/bank,
// free per m136). Epilogue/A-loads unchanged from R1.
__global__ __launch_bounds__(320) void k_qkv(
    const float* __restrict__ x, const ushort* __restrict__ wbf,
    const float* __restrict__ ball,
    ushort* __restrict__ qg, ushort* __restrict__ ktg, ushort* __restrict__ vg)
{
    __shared__ float  xt[256*32];     // 32KB staged x tile [c(256)][n(32)]
    __shared__ ushort tr[5][32*40];   // per-wave 32x32 transpose tile

    int blk = blockIdx.x;
    int b  = blk >> 7;
    int nt = blk & 127;                // n-tile index (32 cols)
    int n0 = nt * 32;
    int t = threadIdx.x;
    int w = t >> 6, lane = t & 63;
    int l31 = lane & 31, h = lane >> 5;

    // bulk x-tile stage: chunk = 8 c-rows x 32 n (1KB); lane i covers
    // row chunk*8 + i/8, floats (i%8)*4 .. +3 (16B per lane).
    const float* xsrc = x + (size_t)b*C_*HW_ + n0;
    if (w < 4) {
        #pragma unroll
        for (int i = 0; i < 8; ++i) {
            int chunk = w*8 + i;
            const float* src = xsrc + (size_t)(chunk*8 + (lane >> 3))*HW_
                               + (lane & 7)*4;
            __builtin_amdgcn_global_load_lds(
                (const __attribute__((address_space(1))) uint32_t*)src,
                (__attribute__((address_space(3))) uint32_t*)&xt[chunk*256],
                16, 0, 0);
        }
    }
    __syncthreads();

    f32x16 acc[2];
    acc[0] = (f32x16)(0.f);
    acc[1] = (f32x16)(0.f);

    #pragma unroll 4
    for (int kc = 0; kc < 16; ++kc) {          // K chunks of 16
        short8 a0 = *(const short8*)(wbf + (kc*10 + w*2    )*512 + lane*8);
        short8 a1 = *(const short8*)(wbf + (kc*10 + w*2 + 1)*512 + lane*8);
        float xv[8];
        #pragma unroll
        for (int j = 0; j < 8; ++j)
            xv[j] = xt[kc*512 + (h*8 + j)*32 + l31];
        union { uint32_t d[4]; short8 s8; } bf;
        #pragma unroll
        for (int j2 = 0; j2 < 4; ++j2) bf.d[j2] = pktr(xv[2*j2], xv[2*j2+1]);
        acc[0] = __builtin_amdgcn_mfma_f32_32x32x16_bf16(a0, bf.s8, acc[0], 0, 0, 0);
        acc[1] = __builtin_amdgcn_mfma_f32_32x32x16_bf16(a1, bf.s8, acc[1], 0, 0, 0);
    }

    // epilogue: per mi subtile, transpose in LDS, store contiguous frags (R1)
    #pragma unroll
    for (int mi = 0; mi < 2; ++mi) {
        int rowb = w*64 + mi*32;
        bool isQK = (rowb < 64);
        #pragma unroll
        for (int r = 0; r < 16; ++r) {
            int roff = (r & 3) + 8*(r >> 2) + 4*h;
            ushort bv = f2bf(acc[mi][r] + ball[rowb + roff]);
            int ad = isQK ? (l31*40 + roff) : (roff*40 + l31);
            tr[w][ad] = bv;
        }
        __syncthreads();
        #pragma unroll
        for (int f = 0; f < 2; ++f) {
            us8 frag = *(const us8*)(&tr[w][l31*40 + f*16 + h*8]);
            if (isQK) {
                ushort* dstb = (rowb == 0) ? qg : ktg;
                size_t ad = ((size_t)((b*128 + nt)*2 + f) << 9) + lane*8;
                *(us8*)(dstb + ad) = frag;
            } else {
                int cblk = (rowb - 64) >> 5;
                int mb = nt*2 + f;
                size_t ad = ((size_t)((b*8 + cblk)*256 + mb) << 9) + lane*8;
                *(us8*)(vg + ad) = frag;
            }
        }
        __syncthreads();
    }
}

// ---------------- kernel 3: flash attention, m-split partials ----------------
// grid = 512: ms=blk&3, cs=bit2, qb=bits[3:6], b=bits[7:8]. 512 thr = 8 waves;
// wave = 32q x 128c, acc 64 AGPR, 4 waves/SIMD. R1-measured best (152.9us).
// R0: permlane32_swap S->PV exchange (T12); setprio around MFMA (T5).
// R1: within-wave 2-stage pipeline. R3/R4/R7 structural variants all
// regressed or null -- this exact body is the measured optimum.
__global__ __launch_bounds__(512, 4) void k_attn(
    const ushort* __restrict__ qg, const ushort* __restrict__ ktg,
    const ushort* __restrict__ vg,
    ushort* __restrict__ pacc, float* __restrict__ lpart)
{
    __shared__ ushort v_lds[2][16*512];   // 16 V frags [cfr*4 + mf]
    __shared__ ushort kt_lds[2][4*512];   // 4 Kt frags [kb*2 + ks]

    int blk = blockIdx.x;
    int ms = blk & 3;
    int cs = (blk >> 2) & 1;
    int qb = (blk >> 3) & 15;
    int b  = blk >> 7;
    int t = threadIdx.x;
    int w = t >> 6, lane = t & 63;
    int l31 = lane & 31, h = lane >> 5;
    int mbase = ms*1024;

    short8 qf[2];
    #pragma unroll
    for (int ks = 0; ks < 2; ++ks)
        qf[ks] = *(const short8*)(qg
            + ((size_t)((b*128 + qb*8 + w)*2 + ks) << 9) + lane*8);

    f32x16 acc[4];
    #pragma unroll
    for (int j = 0; j < 4; ++j) acc[j] = (f32x16)(0.f);
    f32x2 lacc0 = {0.f, 0.f};
    f32x2 lacc1 = {0.f, 0.f};

    #define STAGE(buf, m0)                                                          \
    {                                                                               \
        _Pragma("unroll")                                                           \
        for (int ff = 0; ff < 2; ++ff) {                                            \
            int f = w*2 + ff;                                                       \
            int cfr = f >> 2, mf = f & 3;                                           \
            const ushort* src = vg + ((size_t)((b*8 + cs*4 + cfr)*256               \
                                 + ((m0) >> 4) + mf) << 9) + lane*8;                \
            __builtin_amdgcn_global_load_lds(                                       \
                (const __attribute__((address_space(1))) uint32_t*)src,             \
                (__attribute__((address_space(3))) uint32_t*)&v_lds[buf][f*512],    \
                16, 0, 0);                                                          \
        }                                                                           \
        if (w < 4) {                                                                \
            const ushort* src = ktg + ((size_t)((b*128 + ((m0) >> 5) + (w >> 1))*2  \
                                 + (w & 1)) << 9) + lane*8;                         \
            __builtin_amdgcn_global_load_lds(                                       \
                (const __attribute__((address_space(1))) uint32_t*)src,             \
                (__attribute__((address_space(3))) uint32_t*)&kt_lds[buf][w*512],   \
                16, 0, 0);                                                          \
        }                                                                           \
    }

    #define PMERGE(uu, lo8, hi8)                                                    \
    {                                                                               \
        union { uint32_t d[4]; short8 s8; } fe_, fo_;                               \
        auto r02 = __builtin_amdgcn_permlane32_swap((int)uu[0], (int)uu[2], false, false); \
        auto r13 = __builtin_amdgcn_permlane32_swap((int)uu[1], (int)uu[3], false, false); \
        auto r46 = __builtin_amdgcn_permlane32_swap((int)uu[4], (int)uu[6], false, false); \
        auto r57 = __builtin_amdgcn_permlane32_swap((int)uu[5], (int)uu[7], false, false); \
        fe_.d[0] = (uint32_t)r02[0];  fe_.d[1] = (uint32_t)r13[0];                  \
        fe_.d[2] = (uint32_t)r02[1];  fe_.d[3] = (uint32_t)r13[1];                  \
        fo_.d[0] = (uint32_t)r46[0];  fo_.d[1] = (uint32_t)r57[0];                  \
        fo_.d[2] = (uint32_t)r46[1];  fo_.d[3] = (uint32_t)r57[1];                  \
        lo8 = fe_.s8;  hi8 = fo_.s8;                                               \
    }

    STAGE(0, mbase)
    __syncthreads();

    int buf = 0;
    for (int it = 0; it < 16; ++it) {
        if (it + 1 < 16) STAGE(buf ^ 1, mbase + (it+1)*64)

        // ---- QK kb=0 (head cluster, prio-boosted) ----
        short8 kt0a = *(const short8*)(&kt_lds[buf][0*512 + lane*8]);
        short8 kt1a = *(const short8*)(&kt_lds[buf][1*512 + lane*8]);
        f32x16 s_a = (f32x16)(0.f);
        __builtin_amdgcn_s_setprio(1);
        s_a = __builtin_amdgcn_mfma_f32_32x32x16_bf16(kt0a, qf[0], s_a, 0, 0, 0);
        s_a = __builtin_amdgcn_mfma_f32_32x32x16_bf16(kt1a, qf[1], s_a, 0, 0, 0);
        __builtin_amdgcn_s_setprio(0);

        // ---- SM_a: exp2 + pack + permlane ----
        uint32_t ua[8];
        #pragma unroll
        for (int i = 0; i < 8; ++i) {
            f32x2 e01;
            ua[i] = fexp2_pk(s_a[2*i], s_a[2*i+1], e01);
            if (i & 1) lacc1 += e01; else lacc0 += e01;
        }
        short8 pfa0, pfa1;
        PMERGE(ua, pfa0, pfa1)

        // ---- QK kb=1 (issued early; executes under SM_a tail / PV_a head) ----
        short8 kt0b = *(const short8*)(&kt_lds[buf][2*512 + lane*8]);
        short8 kt1b = *(const short8*)(&kt_lds[buf][3*512 + lane*8]);
        f32x16 s_b = (f32x16)(0.f);
        s_b = __builtin_amdgcn_mfma_f32_32x32x16_bf16(kt0b, qf[0], s_b, 0, 0, 0);
        s_b = __builtin_amdgcn_mfma_f32_32x32x16_bf16(kt1b, qf[1], s_b, 0, 0, 0);

        // ---- fence-free region: SM_b VALU interleaves with PV_a MFMA ----
        uint32_t ub[8];
        #pragma unroll
        for (int i = 0; i < 8; ++i) {
            f32x2 e01;
            ub[i] = fexp2_pk(s_b[2*i], s_b[2*i+1], e01);
            if (i & 1) lacc1 += e01; else lacc0 += e01;
        }
        #pragma unroll
        for (int msub = 0; msub < 2; ++msub) {     // PV_a: keys [0,32)
            short8 pfm = msub ? pfa1 : pfa0;
            int ks16 = msub;
            #pragma unroll
            for (int cfr = 0; cfr < 4; ++cfr) {
                short8 vf = *(const short8*)(&v_lds[buf][(cfr*4 + ks16)*512 + lane*8]);
                acc[cfr] = __builtin_amdgcn_mfma_f32_32x32x16_bf16(vf, pfm, acc[cfr], 0, 0, 0);
            }
        }
        short8 pfb0, pfb1;
        PMERGE(ub, pfb0, pfb1)

        // ---- PV_b (tail cluster, prio-boosted) ----
        __builtin_amdgcn_s_setprio(1);
        #pragma unroll
        for (int msub = 0; msub < 2; ++msub) {     // keys [32,64)
            short8 pfm = msub ? pfb1 : pfb0;
            int ks16 = 2 + msub;
            #pragma unroll
            for (int cfr = 0; cfr < 4; ++cfr) {
                short8 vf = *(const short8*)(&v_lds[buf][(cfr*4 + ks16)*512 + lane*8]);
                acc[cfr] = __builtin_amdgcn_mfma_f32_32x32x16_bf16(vf, pfm, acc[cfr], 0, 0, 0);
            }
        }
        __builtin_amdgcn_s_setprio(0);

        __syncthreads();
        buf ^= 1;
    }

    // finalize l: horizontal + other lane-half's key contributions
    f32x2 lacc = lacc0 + lacc1;
    float lsum = lacc.x + lacc.y;
    {
        union { float f; int i; } cv; cv.f = lsum;
        cv.i = __shfl_xor(cv.i, 32);
        lsum += cv.f;
    }
    if (cs == 0 && h == 0)
        lpart[(size_t)(ms*B_ + b)*HW_ + qb*256 + w*32 + l31] = lsum;

    // pacc raw fragment dump: contiguous 2KB per cfr wave-store
    int blkl = ((ms*B_ + b)*16 + qb)*2 + cs;
    #pragma unroll
    for (int cfr = 0; cfr < 4; ++cfr) {
        union { uint32_t d[8]; us8 hlf[2]; } pk;
        #pragma unroll
        for (int i = 0; i < 8; ++i)
            pk.d[i] = pktr(acc[cfr][2*i], acc[cfr][2*i+1]);
        ushort* dst = pacc + ((size_t)(blkl*32 + w*4 + cfr) << 10);
        *(us8*)(dst + lane*8)       = pk.hlf[0];
        *(us8*)(dst + 512 + lane*8) = pk.hlf[1];
    }
    #undef STAGE
    #undef PMERGE
}

// ---------------- kernel 4: combine via LDS transpose + epilogue ----------
// grid = 1024 blocks (b,qb,cs,w), 256 thr. Phase 1: frag-native decode +
// gamma/l fold -> LDS [128c][36]. Phase 2: float4 x/out (full lines).
__global__ __launch_bounds__(256) void k_comb(
    const ushort* __restrict__ pacc, const float* __restrict__ lpart,
    const float* __restrict__ x, const float* __restrict__ gamma_p,
    float* __restrict__ out)
{
    __shared__ float lds_acc[128*36];   // 18.4 KB

    int blk = blockIdx.x;
    int w  = blk & 7;
    int cs = (blk >> 3) & 1;
    int qb = (blk >> 4) & 15;
    int b  = blk >> 8;
    int t = threadIdx.x;

    int l31 = t & 31;
    int h   = (t >> 5) & 1;
    int cfr = (t >> 6) & 3;
    int q = qb*256 + w*32 + l31;
    int lanef = h*32 + l31;

    float sum[16];
    #pragma unroll
    for (int k = 0; k < 16; ++k) sum[k] = 0.f;
    float lt = 0.f;

    #pragma unroll
    for (int ms = 0; ms < MS_; ++ms) {
        int blkl = ((ms*B_ + b)*16 + qb)*2 + cs;
        const ushort* pp = pacc + ((size_t)(blkl*32 + w*4 + cfr) << 10) + lanef*8;
        us8 a0 = *(const us8*)pp;
        us8 a1 = *(const us8*)(pp + 512);
        #pragma unroll
        for (int k = 0; k < 8; ++k) {
            union { uint32_t u; float f; } cv;
            cv.u = ((uint32_t)a0[k]) << 16;  sum[k]   += cv.f;
            cv.u = ((uint32_t)a1[k]) << 16;  sum[k+8] += cv.f;
        }
        lt += lpart[(size_t)(ms*B_ + b)*HW_ + q];
    }

    float rl = gamma_p[0] / lt;
    #pragma unroll
    for (int k = 0; k < 16; ++k) {
        int c = cfr*32 + (k & 3) + 8*(k >> 2) + 4*h;
        lds_acc[c*36 + l31] = sum[k]*rl;
    }
    __syncthreads();

    // phase 2: 1024 float4 slots [c(128)][qg(8)]; thread does 4 slots
    const float* xb = x + ((size_t)(b*C_ + cs*128))*HW_ + qb*256 + w*32;
    float* ob = out + ((size_t)(b*C_ + cs*128))*HW_ + qb*256 + w*32;
    #pragma unroll
    for (int i = 0; i < 4; ++i) {
        int s = t + i*256;
        int c = s >> 3, qg = s & 7;
        float4 a = *(const float4*)(&lds_acc[c*36 + qg*4]);
        size_t off = (size_t)c*HW_ + qg*4;
        float4 xv = *(const float4*)(xb + off);
        a.x += xv.x; a.y += xv.y; a.z += xv.z; a.w += xv.w;
        *(float4*)(ob + off) = a;
    }
}

extern "C" void kernel_launch(void* const* d_in, const int* in_sizes, int n_in,
                              void* d_out, int out_size, void* d_ws, size_t ws_size,
                              hipStream_t stream)
{
    const float* x      = (const float*)d_in[0];
    const float* conv_w = (const float*)d_in[1];
    const float* conv_b = (const float*)d_in[2];
    const float* q_w    = (const float*)d_in[3];
    const float* q_b    = (const float*)d_in[4];
    const float* k_w    = (const float*)d_in[5];
    const float* k_b    = (const float*)d_in[6];
    const float* v_w    = (const float*)d_in[7];
    const float* v_b    = (const float*)d_in[8];
    const float* gamma  = (const float*)d_in[9];
    float* out = (float*)d_out;

    char* ws = (char*)d_ws;
    ushort* wbf   = (ushort*)(ws + WT_OFF);
    float*  ball  = (float*)(ws + BALL_OFF);
    ushort* qg    = (ushort*)(ws + Q_OFF);
    ushort* ktg   = (ushort*)(ws + KT_OFF);
    ushort* vg    = (ushort*)(ws + V_OFF);
    ushort* pacc  = (ushort*)(ws + PACC_OFF);
    float*  lpart = (float*)(ws + LPART_OFF);

    k_setup<<<ROWS_, 256, 0, stream>>>(conv_w, conv_b, q_w, q_b, k_w, k_b,
                                       v_w, v_b, wbf, ball);
    k_qkv<<<B_*128, 320, 0, stream>>>(x, wbf, ball, qg, ktg, vg);
    k_attn<<<512, 512, 0, stream>>>(qg, ktg, vg, pacc, lpart);
    k_comb<<<1024, 256, 0, stream>>>(pacc, lpart, x, gamma, out);
}